// Round 3
// baseline (1686.265 us; speedup 1.0000x reference)
//
#include <hip/hip_runtime.h>
#include <math.h>

#define NN 100000
#define NE 3200000
#define IN_F 7
#define H 32

// ---------------- kernel 1: node encoder + GCN weight ----------------
// h = relu(x @ W_enc + b_enc);  hW = h @ W_gcn   (b_gcn added later)
__global__ __launch_bounds__(256) void k_encode(const float* __restrict__ x,
                                                const float* __restrict__ Wenc,
                                                const float* __restrict__ benc,
                                                const float* __restrict__ Wgcn,
                                                float* __restrict__ hW) {
    __shared__ float sWe[IN_F * H];
    __shared__ float sb[H];
    __shared__ float sWg[H * H];
    for (int i = threadIdx.x; i < IN_F * H; i += 256) sWe[i] = Wenc[i];
    for (int i = threadIdx.x; i < H; i += 256) sb[i] = benc[i];
    for (int i = threadIdx.x; i < H * H; i += 256) sWg[i] = Wgcn[i];
    __syncthreads();

    int n = blockIdx.x * 256 + threadIdx.x;
    if (n >= NN) return;

    float xl[IN_F];
#pragma unroll
    for (int j = 0; j < IN_F; ++j) xl[j] = x[n * IN_F + j];

    float h[H];
#pragma unroll
    for (int k = 0; k < H; ++k) {
        float a = sb[k];
#pragma unroll
        for (int j = 0; j < IN_F; ++j) a = fmaf(xl[j], sWe[j * H + k], a);
        h[k] = fmaxf(a, 0.f);
    }
#pragma unroll
    for (int k = 0; k < H; ++k) {
        float a = 0.f;
#pragma unroll
        for (int j = 0; j < H; ++j) a = fmaf(h[j], sWg[j * H + k], a);
        hW[n * H + k] = a;
    }
}

// ---------------- kernel 2: in-degree (dst) ----------------
__global__ __launch_bounds__(256) void k_deg(const int* __restrict__ dst,
                                             int* __restrict__ deg) {
    int e = blockIdx.x * 256 + threadIdx.x;
    if (e < NE) atomicAdd(&deg[dst[e]], 1);
}

// ---------------- kernel 3: dinv = rsqrt(deg + 1) ----------------
__global__ __launch_bounds__(256) void k_dinv(const int* __restrict__ deg,
                                              float* __restrict__ dinv) {
    int n = blockIdx.x * 256 + threadIdx.x;
    if (n < NN) dinv[n] = rsqrtf((float)deg[n] + 1.0f);
}

// ---------------- kernel 4: scatter-add  agg[dst] += hW[src]*norm ----------------
// 8 threads per edge, one float4 chunk each.
__global__ __launch_bounds__(256) void k_scatter(const int* __restrict__ src,
                                                 const int* __restrict__ dst,
                                                 const float* __restrict__ dinv,
                                                 const float* __restrict__ hW,
                                                 float* __restrict__ agg) {
    int t = blockIdx.x * 256 + threadIdx.x;
    int e = t >> 3;
    int c = t & 7;
    if (e >= NE) return;
    int s = src[e];
    int d = dst[e];
    float norm = dinv[s] * dinv[d];
    float4 v = *reinterpret_cast<const float4*>(hW + s * H + c * 4);
    float* ap = agg + d * H + c * 4;
    atomicAdd(ap + 0, v.x * norm);
    atomicAdd(ap + 1, v.y * norm);
    atomicAdd(ap + 2, v.z * norm);
    atomicAdd(ap + 3, v.w * norm);
}

// ---------------- kernel 5: h2 = relu(agg + hW*dinv^2 + b_gcn), in-place ----------------
__global__ __launch_bounds__(256) void k_final(float* __restrict__ agg_h2,
                                               const float* __restrict__ hW,
                                               const float* __restrict__ dinv,
                                               const float* __restrict__ bgcn) {
    int i = blockIdx.x * 256 + threadIdx.x;
    if (i >= NN * H) return;
    int n = i >> 5;
    int k = i & 31;
    float di = dinv[n];
    float v = agg_h2[i] + hW[i] * (di * di) + bgcn[k];
    agg_h2[i] = fmaxf(v, 0.f);
}

// ---------------- kernel 6: edge scorer ----------------
__global__ __launch_bounds__(256) void k_score(const int* __restrict__ src,
                                               const int* __restrict__ dst,
                                               const float* __restrict__ h2,
                                               const float* __restrict__ We,
                                               const float* __restrict__ be,
                                               float* __restrict__ out) {
    __shared__ float sW[2 * H];
    __shared__ float sB;
    if (threadIdx.x < 2 * H) sW[threadIdx.x] = We[threadIdx.x];
    if (threadIdx.x == 0) sB = be[0];
    __syncthreads();

    int e = blockIdx.x * 256 + threadIdx.x;
    if (e >= NE) return;
    int s = src[e];
    int d = dst[e];
    const float4* hs = reinterpret_cast<const float4*>(h2 + s * H);
    const float4* hd = reinterpret_cast<const float4*>(h2 + d * H);
    float acc = sB;
#pragma unroll
    for (int q = 0; q < 8; ++q) {
        float4 a = hs[q];
        float4 b = hd[q];
        acc = fmaf(a.x, sW[q * 4 + 0], acc);
        acc = fmaf(a.y, sW[q * 4 + 1], acc);
        acc = fmaf(a.z, sW[q * 4 + 2], acc);
        acc = fmaf(a.w, sW[q * 4 + 3], acc);
        acc = fmaf(b.x, sW[H + q * 4 + 0], acc);
        acc = fmaf(b.y, sW[H + q * 4 + 1], acc);
        acc = fmaf(b.z, sW[H + q * 4 + 2], acc);
        acc = fmaf(b.w, sW[H + q * 4 + 3], acc);
    }
    float sc = 1.0f / (1.0f + __expf(-acc));
    __builtin_nontemporal_store(sc, &out[e]);
}

extern "C" void kernel_launch(void* const* d_in, const int* in_sizes, int n_in,
                              void* d_out, int out_size, void* d_ws, size_t ws_size,
                              hipStream_t stream) {
    const float* x_t   = (const float*)d_in[0];
    // d_in[1] (x_t_dt) is unused by the reference
    const int*   eidx  = (const int*)d_in[2];
    const float* Wenc  = (const float*)d_in[3];
    const float* benc  = (const float*)d_in[4];
    const float* Wgcn  = (const float*)d_in[5];
    const float* bgcn  = (const float*)d_in[6];
    const float* Wedge = (const float*)d_in[7];
    const float* bedge = (const float*)d_in[8];
    float* out = (float*)d_out;

    const int* src = eidx;
    const int* dst = eidx + NE;

    // workspace layout (bytes)
    char* ws = (char*)d_ws;
    float* hW   = (float*)(ws);                       // 12,800,000 B
    float* agg  = (float*)(ws + 12800000);            // 12,800,000 B (becomes h2 in-place)
    int*   deg  = (int*)  (ws + 25600000);            //    400,000 B
    float* dinv = (float*)(ws + 26000256);            //    400,000 B

    hipMemsetAsync(agg, 0, (size_t)NN * H * sizeof(float), stream);
    hipMemsetAsync(deg, 0, (size_t)NN * sizeof(int), stream);

    k_encode<<<(NN + 255) / 256, 256, 0, stream>>>(x_t, Wenc, benc, Wgcn, hW);
    k_deg<<<(NE + 255) / 256, 256, 0, stream>>>(dst, deg);
    k_dinv<<<(NN + 255) / 256, 256, 0, stream>>>(deg, dinv);
    k_scatter<<<(NE * 8 + 255) / 256, 256, 0, stream>>>(src, dst, dinv, hW, agg);
    k_final<<<(NN * H + 255) / 256, 256, 0, stream>>>(agg, hW, dinv, bgcn);
    k_score<<<(NE + 255) / 256, 256, 0, stream>>>(src, dst, agg, Wedge, bedge, out);
}

// Round 5
// 1007.585 us; speedup vs baseline: 1.6736x; 1.6736x over previous
//
#include <hip/hip_runtime.h>
#include <math.h>

#define NN 100000
#define NE 3200000
#define IN_F 7
#define H 32

#define SCAN_T 1024
#define CHUNK ((NN + SCAN_T - 1) / SCAN_T)  // 98

// ---------------- kernel 1: node encoder + GCN weight ----------------
__global__ __launch_bounds__(256) void k_encode(const float* __restrict__ x,
                                                const float* __restrict__ Wenc,
                                                const float* __restrict__ benc,
                                                const float* __restrict__ Wgcn,
                                                float* __restrict__ hW) {
    __shared__ float sWe[IN_F * H];
    __shared__ float sb[H];
    __shared__ float sWg[H * H];
    for (int i = threadIdx.x; i < IN_F * H; i += 256) sWe[i] = Wenc[i];
    for (int i = threadIdx.x; i < H; i += 256) sb[i] = benc[i];
    for (int i = threadIdx.x; i < H * H; i += 256) sWg[i] = Wgcn[i];
    __syncthreads();

    int n = blockIdx.x * 256 + threadIdx.x;
    if (n >= NN) return;

    float xl[IN_F];
#pragma unroll
    for (int j = 0; j < IN_F; ++j) xl[j] = x[n * IN_F + j];

    float h[H];
#pragma unroll
    for (int k = 0; k < H; ++k) {
        float a = sb[k];
#pragma unroll
        for (int j = 0; j < IN_F; ++j) a = fmaf(xl[j], sWe[j * H + k], a);
        h[k] = fmaxf(a, 0.f);
    }
#pragma unroll
    for (int k = 0; k < H; ++k) {
        float a = 0.f;
#pragma unroll
        for (int j = 0; j < H; ++j) a = fmaf(h[j], sWg[j * H + k], a);
        hW[n * H + k] = a;
    }
}

// ---------------- kernel 2: in-degree (dst) ----------------
__global__ __launch_bounds__(256) void k_deg(const int* __restrict__ dst,
                                             int* __restrict__ deg) {
    int e = blockIdx.x * 256 + threadIdx.x;
    if (e < NE) atomicAdd(&deg[dst[e]], 1);
}

// ---------------- kernel 3: single-block scan -> row_ptr, wptr, dinv ----------------
__global__ __launch_bounds__(SCAN_T) void k_scan(const int* __restrict__ deg,
                                                 int* __restrict__ row_ptr,
                                                 int* __restrict__ wptr,
                                                 float* __restrict__ dinv) {
    __shared__ int tmp[SCAN_T];
    int t = threadIdx.x;
    int base = t * CHUNK;
    int lim = min(base + CHUNK, NN);
    int s = 0;
    for (int i = base; i < lim; ++i) s += deg[i];
    tmp[t] = s;
    __syncthreads();
    for (int off = 1; off < SCAN_T; off <<= 1) {
        int v = (t >= off) ? tmp[t - off] : 0;
        __syncthreads();
        tmp[t] += v;
        __syncthreads();
    }
    int run = tmp[t] - s;  // exclusive prefix
    for (int i = base; i < lim; ++i) {
        int d = deg[i];
        row_ptr[i] = run;
        wptr[i] = run;
        dinv[i] = rsqrtf((float)d + 1.0f);
        run += d;
    }
    if (t == SCAN_T - 1) row_ptr[NN] = run;  // == NE
}

// ---------------- kernel 4: CSR fill ----------------
__global__ __launch_bounds__(256) void k_fill(const int* __restrict__ src,
                                              const int* __restrict__ dst,
                                              int* __restrict__ wptr,
                                              int* __restrict__ csr_src) {
    int e = blockIdx.x * 256 + threadIdx.x;
    if (e >= NE) return;
    int d = dst[e];
    int pos = atomicAdd(&wptr[d], 1);
    csr_src[pos] = src[e];
}

// ---------------- kernel 5: per-node gather + epilogue (fused k_final) ----------------
// 8 lanes per node, each lane owns a float4 chunk of H=32.
__global__ __launch_bounds__(256) void k_gather(const int* __restrict__ row_ptr,
                                                const int* __restrict__ csr_src,
                                                const float* __restrict__ dinv,
                                                const float* __restrict__ hW,
                                                const float* __restrict__ bgcn,
                                                float* __restrict__ h2) {
    int tid = blockIdx.x * 256 + threadIdx.x;
    int n = tid >> 3;
    int c = tid & 7;
    if (n >= NN) return;
    float dn = dinv[n];
    int beg = row_ptr[n], end = row_ptr[n + 1];
    const float4* hW4 = reinterpret_cast<const float4*>(hW);
    float4 acc = make_float4(0.f, 0.f, 0.f, 0.f);
    for (int k = beg; k < end; ++k) {
        int s = csr_src[k];
        float nrm = dinv[s] * dn;
        float4 v = hW4[s * 8 + c];
        acc.x = fmaf(v.x, nrm, acc.x);
        acc.y = fmaf(v.y, nrm, acc.y);
        acc.z = fmaf(v.z, nrm, acc.z);
        acc.w = fmaf(v.w, nrm, acc.w);
    }
    float4 w = hW4[n * 8 + c];
    float sl = dn * dn;
    float4 b = reinterpret_cast<const float4*>(bgcn)[c];
    float4 r;
    r.x = fmaxf(acc.x + w.x * sl + b.x, 0.f);
    r.y = fmaxf(acc.y + w.y * sl + b.y, 0.f);
    r.z = fmaxf(acc.z + w.z * sl + b.z, 0.f);
    r.w = fmaxf(acc.w + w.w * sl + b.w, 0.f);
    reinterpret_cast<float4*>(h2)[n * 8 + c] = r;
}

// ---------------- fallback path kernels (atomic scatter), used only if ws too small ----
__global__ __launch_bounds__(256) void k_dinv_fb(const int* __restrict__ deg,
                                                 float* __restrict__ dinv) {
    int n = blockIdx.x * 256 + threadIdx.x;
    if (n < NN) dinv[n] = rsqrtf((float)deg[n] + 1.0f);
}

__global__ __launch_bounds__(256) void k_scatter_fb(const int* __restrict__ src,
                                                    const int* __restrict__ dst,
                                                    const float* __restrict__ dinv,
                                                    const float* __restrict__ hW,
                                                    float* __restrict__ agg) {
    int t = blockIdx.x * 256 + threadIdx.x;
    int e = t >> 3;
    int c = t & 7;
    if (e >= NE) return;
    int s = src[e];
    int d = dst[e];
    float norm = dinv[s] * dinv[d];
    float4 v = *reinterpret_cast<const float4*>(hW + s * H + c * 4);
    float* ap = agg + d * H + c * 4;
    atomicAdd(ap + 0, v.x * norm);
    atomicAdd(ap + 1, v.y * norm);
    atomicAdd(ap + 2, v.z * norm);
    atomicAdd(ap + 3, v.w * norm);
}

__global__ __launch_bounds__(256) void k_final_fb(float* __restrict__ agg_h2,
                                                  const float* __restrict__ hW,
                                                  const float* __restrict__ dinv,
                                                  const float* __restrict__ bgcn) {
    int i = blockIdx.x * 256 + threadIdx.x;
    if (i >= NN * H) return;
    int n = i >> 5;
    int k = i & 31;
    float di = dinv[n];
    float v = agg_h2[i] + hW[i] * (di * di) + bgcn[k];
    agg_h2[i] = fmaxf(v, 0.f);
}

// ---------------- kernel 6: edge scorer ----------------
__global__ __launch_bounds__(256) void k_score(const int* __restrict__ src,
                                               const int* __restrict__ dst,
                                               const float* __restrict__ h2,
                                               const float* __restrict__ We,
                                               const float* __restrict__ be,
                                               float* __restrict__ out) {
    __shared__ float sW[2 * H];
    __shared__ float sB;
    if (threadIdx.x < 2 * H) sW[threadIdx.x] = We[threadIdx.x];
    if (threadIdx.x == 0) sB = be[0];
    __syncthreads();

    int e = blockIdx.x * 256 + threadIdx.x;
    if (e >= NE) return;
    int s = src[e];
    int d = dst[e];
    const float4* hs = reinterpret_cast<const float4*>(h2 + s * H);
    const float4* hd = reinterpret_cast<const float4*>(h2 + d * H);
    float acc = sB;
#pragma unroll
    for (int q = 0; q < 8; ++q) {
        float4 a = hs[q];
        float4 b = hd[q];
        acc = fmaf(a.x, sW[q * 4 + 0], acc);
        acc = fmaf(a.y, sW[q * 4 + 1], acc);
        acc = fmaf(a.z, sW[q * 4 + 2], acc);
        acc = fmaf(a.w, sW[q * 4 + 3], acc);
        acc = fmaf(b.x, sW[H + q * 4 + 0], acc);
        acc = fmaf(b.y, sW[H + q * 4 + 1], acc);
        acc = fmaf(b.z, sW[H + q * 4 + 2], acc);
        acc = fmaf(b.w, sW[H + q * 4 + 3], acc);
    }
    float sc = 1.0f / (1.0f + __expf(-acc));
    __builtin_nontemporal_store(sc, &out[e]);
}

extern "C" void kernel_launch(void* const* d_in, const int* in_sizes, int n_in,
                              void* d_out, int out_size, void* d_ws, size_t ws_size,
                              hipStream_t stream) {
    const float* x_t   = (const float*)d_in[0];
    // d_in[1] (x_t_dt) unused by the reference
    const int*   eidx  = (const int*)d_in[2];
    const float* Wenc  = (const float*)d_in[3];
    const float* benc  = (const float*)d_in[4];
    const float* Wgcn  = (const float*)d_in[5];
    const float* bgcn  = (const float*)d_in[6];
    const float* Wedge = (const float*)d_in[7];
    const float* bedge = (const float*)d_in[8];
    float* out = (float*)d_out;

    const int* src = eidx;
    const int* dst = eidx + NE;

    char* ws = (char*)d_ws;

    if (ws_size >= 40100000) {
        // CSR path. Layout (bytes):
        float* hW      = (float*)(ws);                  // 12,800,000
        float* h2      = (float*)(ws + 12800000);       // 12,800,000
        int*   csr_src = (int*)  (ws + 25600000);       // 12,800,000
        int*   deg     = (int*)  (ws + 38400000);       //    400,000
        float* dinv    = (float*)(ws + 38800000);       //    400,000
        int*   row_ptr = (int*)  (ws + 39200000);       //    400,004
        int*   wptr    = (int*)  (ws + 39600064);       //    400,000

        hipMemsetAsync(deg, 0, (size_t)NN * sizeof(int), stream);

        k_encode<<<(NN + 255) / 256, 256, 0, stream>>>(x_t, Wenc, benc, Wgcn, hW);
        k_deg<<<(NE + 255) / 256, 256, 0, stream>>>(dst, deg);
        k_scan<<<1, SCAN_T, 0, stream>>>(deg, row_ptr, wptr, dinv);
        k_fill<<<(NE + 255) / 256, 256, 0, stream>>>(src, dst, wptr, csr_src);
        k_gather<<<(NN * 8 + 255) / 256, 256, 0, stream>>>(row_ptr, csr_src, dinv, hW, bgcn, h2);
        k_score<<<(NE + 255) / 256, 256, 0, stream>>>(src, dst, h2, Wedge, bedge, out);
    } else {
        // fallback: proven atomic-scatter path
        float* hW   = (float*)(ws);
        float* agg  = (float*)(ws + 12800000);
        int*   deg  = (int*)  (ws + 25600000);
        float* dinv = (float*)(ws + 26000256);

        hipMemsetAsync(agg, 0, (size_t)NN * H * sizeof(float), stream);
        hipMemsetAsync(deg, 0, (size_t)NN * sizeof(int), stream);

        k_encode<<<(NN + 255) / 256, 256, 0, stream>>>(x_t, Wenc, benc, Wgcn, hW);
        k_deg<<<(NE + 255) / 256, 256, 0, stream>>>(dst, deg);
        k_dinv_fb<<<(NN + 255) / 256, 256, 0, stream>>>(deg, dinv);
        k_scatter_fb<<<(NE * 8 + 255) / 256, 256, 0, stream>>>(src, dst, dinv, hW, agg);
        k_final_fb<<<(NN * H + 255) / 256, 256, 0, stream>>>(agg, hW, dinv, bgcn);
        k_score<<<(NE + 255) / 256, 256, 0, stream>>>(src, dst, agg, Wedge, bedge, out);
    }
}

// Round 7
// 895.401 us; speedup vs baseline: 1.8833x; 1.1253x over previous
//
#include <hip/hip_runtime.h>
#include <math.h>

#define NN 100000
#define NE 3200000
#define IN_F 7
#define H 32
#define NS 16            // shadow copies for atomic privatization

#define SCAN_T 1024
#define CHUNK ((NN + SCAN_T - 1) / SCAN_T)  // 98

// ---------------- kernel 1: node encoder + GCN weight ----------------
__global__ __launch_bounds__(256) void k_encode(const float* __restrict__ x,
                                                const float* __restrict__ Wenc,
                                                const float* __restrict__ benc,
                                                const float* __restrict__ Wgcn,
                                                float* __restrict__ hW) {
    __shared__ float sWe[IN_F * H];
    __shared__ float sb[H];
    __shared__ float sWg[H * H];
    for (int i = threadIdx.x; i < IN_F * H; i += 256) sWe[i] = Wenc[i];
    for (int i = threadIdx.x; i < H; i += 256) sb[i] = benc[i];
    for (int i = threadIdx.x; i < H * H; i += 256) sWg[i] = Wgcn[i];
    __syncthreads();

    int n = blockIdx.x * 256 + threadIdx.x;
    if (n >= NN) return;

    float xl[IN_F];
#pragma unroll
    for (int j = 0; j < IN_F; ++j) xl[j] = x[n * IN_F + j];

    float h[H];
#pragma unroll
    for (int k = 0; k < H; ++k) {
        float a = sb[k];
#pragma unroll
        for (int j = 0; j < IN_F; ++j) a = fmaf(xl[j], sWe[j * H + k], a);
        h[k] = fmaxf(a, 0.f);
    }
#pragma unroll
    for (int k = 0; k < H; ++k) {
        float a = 0.f;
#pragma unroll
        for (int j = 0; j < H; ++j) a = fmaf(h[j], sWg[j * H + k], a);
        hW[n * H + k] = a;
    }
}

// ---------------- kernel 2: in-degree into 16 shadow histograms ----------------
__global__ __launch_bounds__(256) void k_deg16(const int* __restrict__ dst,
                                               int* __restrict__ deg16) {
    int e = blockIdx.x * 256 + threadIdx.x;
    if (e < NE) atomicAdd(&deg16[(blockIdx.x & (NS - 1)) * NN + dst[e]], 1);
}

// ---------------- s1: per-node prefix over shadows (in place) + total + dinv ----
__global__ __launch_bounds__(256) void k_s1(int* __restrict__ deg16,
                                            int* __restrict__ degt,
                                            float* __restrict__ dinv) {
    int n = blockIdx.x * 256 + threadIdx.x;
    if (n >= NN) return;
    int run = 0;
#pragma unroll
    for (int c = 0; c < NS; ++c) {
        int v = deg16[c * NN + n];
        deg16[c * NN + n] = run;   // exclusive intra-node prefix
        run += v;
    }
    degt[n] = run;
    dinv[n] = rsqrtf((float)run + 1.0f);
}

// ---------------- s2: single-block global exclusive scan -> row_ptr ----------------
__global__ __launch_bounds__(SCAN_T) void k_s2(const int* __restrict__ degt,
                                               int* __restrict__ row_ptr) {
    __shared__ int tmp[SCAN_T];
    int t = threadIdx.x;
    int base = t * CHUNK;
    int lim = min(base + CHUNK, NN);
    int s = 0;
    for (int i = base; i < lim; ++i) s += degt[i];
    tmp[t] = s;
    __syncthreads();
    for (int off = 1; off < SCAN_T; off <<= 1) {
        int v = (t >= off) ? tmp[t - off] : 0;
        __syncthreads();
        tmp[t] += v;
        __syncthreads();
    }
    int run = tmp[t] - s;  // exclusive prefix
    for (int i = base; i < lim; ++i) {
        row_ptr[i] = run;
        run += degt[i];
    }
    if (t == SCAN_T - 1) row_ptr[NN] = run;  // == NE
}

// ---------------- s3: cursors = intra-prefix + row base (in place) ----------------
__global__ __launch_bounds__(256) void k_s3(int* __restrict__ wptr16,
                                            const int* __restrict__ row_ptr) {
    int n = blockIdx.x * 256 + threadIdx.x;
    if (n >= NN) return;
    int r = row_ptr[n];
#pragma unroll
    for (int c = 0; c < NS; ++c) wptr16[c * NN + n] += r;
}

// ---------------- kernel 4: CSR fill with privatized cursors ----------------
__global__ __launch_bounds__(256) void k_fill16(const int* __restrict__ src,
                                                const int* __restrict__ dst,
                                                int* __restrict__ wptr16,
                                                int* __restrict__ csr_src) {
    int e = blockIdx.x * 256 + threadIdx.x;
    if (e >= NE) return;
    int d = dst[e];
    int pos = atomicAdd(&wptr16[(blockIdx.x & (NS - 1)) * NN + d], 1);
    csr_src[pos] = src[e];
}

// ---------------- kernel 5: per-node gather + epilogue ----------------
// 8 lanes per node, each lane owns a float4 chunk of H=32.
__global__ __launch_bounds__(256) void k_gather(const int* __restrict__ row_ptr,
                                                const int* __restrict__ csr_src,
                                                const float* __restrict__ dinv,
                                                const float* __restrict__ hW,
                                                const float* __restrict__ bgcn,
                                                float* __restrict__ h2) {
    int tid = blockIdx.x * 256 + threadIdx.x;
    int n = tid >> 3;
    int c = tid & 7;
    if (n >= NN) return;
    float dn = dinv[n];
    int beg = row_ptr[n], end = row_ptr[n + 1];
    const float4* hW4 = reinterpret_cast<const float4*>(hW);
    float4 acc = make_float4(0.f, 0.f, 0.f, 0.f);
    for (int k = beg; k < end; ++k) {
        int s = csr_src[k];
        float nrm = dinv[s] * dn;
        float4 v = hW4[s * 8 + c];
        acc.x = fmaf(v.x, nrm, acc.x);
        acc.y = fmaf(v.y, nrm, acc.y);
        acc.z = fmaf(v.z, nrm, acc.z);
        acc.w = fmaf(v.w, nrm, acc.w);
    }
    float4 w = hW4[n * 8 + c];
    float sl = dn * dn;
    float4 b = reinterpret_cast<const float4*>(bgcn)[c];
    float4 r;
    r.x = fmaxf(acc.x + w.x * sl + b.x, 0.f);
    r.y = fmaxf(acc.y + w.y * sl + b.y, 0.f);
    r.z = fmaxf(acc.z + w.z * sl + b.z, 0.f);
    r.w = fmaxf(acc.w + w.w * sl + b.w, 0.f);
    reinterpret_cast<float4*>(h2)[n * 8 + c] = r;
}

// ---------------- fallback path kernels (atomic scatter) ----------------
__global__ __launch_bounds__(256) void k_deg_fb(const int* __restrict__ dst,
                                                int* __restrict__ deg) {
    int e = blockIdx.x * 256 + threadIdx.x;
    if (e < NE) atomicAdd(&deg[dst[e]], 1);
}

__global__ __launch_bounds__(256) void k_dinv_fb(const int* __restrict__ deg,
                                                 float* __restrict__ dinv) {
    int n = blockIdx.x * 256 + threadIdx.x;
    if (n < NN) dinv[n] = rsqrtf((float)deg[n] + 1.0f);
}

__global__ __launch_bounds__(256) void k_scatter_fb(const int* __restrict__ src,
                                                    const int* __restrict__ dst,
                                                    const float* __restrict__ dinv,
                                                    const float* __restrict__ hW,
                                                    float* __restrict__ agg) {
    int t = blockIdx.x * 256 + threadIdx.x;
    int e = t >> 3;
    int c = t & 7;
    if (e >= NE) return;
    int s = src[e];
    int d = dst[e];
    float norm = dinv[s] * dinv[d];
    float4 v = *reinterpret_cast<const float4*>(hW + s * H + c * 4);
    float* ap = agg + d * H + c * 4;
    atomicAdd(ap + 0, v.x * norm);
    atomicAdd(ap + 1, v.y * norm);
    atomicAdd(ap + 2, v.z * norm);
    atomicAdd(ap + 3, v.w * norm);
}

__global__ __launch_bounds__(256) void k_final_fb(float* __restrict__ agg_h2,
                                                  const float* __restrict__ hW,
                                                  const float* __restrict__ dinv,
                                                  const float* __restrict__ bgcn) {
    int i = blockIdx.x * 256 + threadIdx.x;
    if (i >= NN * H) return;
    int n = i >> 5;
    int k = i & 31;
    float di = dinv[n];
    float v = agg_h2[i] + hW[i] * (di * di) + bgcn[k];
    agg_h2[i] = fmaxf(v, 0.f);
}

// ---------------- kernel 6: edge scorer ----------------
__global__ __launch_bounds__(256) void k_score(const int* __restrict__ src,
                                               const int* __restrict__ dst,
                                               const float* __restrict__ h2,
                                               const float* __restrict__ We,
                                               const float* __restrict__ be,
                                               float* __restrict__ out) {
    __shared__ float sW[2 * H];
    __shared__ float sB;
    if (threadIdx.x < 2 * H) sW[threadIdx.x] = We[threadIdx.x];
    if (threadIdx.x == 0) sB = be[0];
    __syncthreads();

    int e = blockIdx.x * 256 + threadIdx.x;
    if (e >= NE) return;
    int s = src[e];
    int d = dst[e];
    const float4* hs = reinterpret_cast<const float4*>(h2 + s * H);
    const float4* hd = reinterpret_cast<const float4*>(h2 + d * H);
    float acc = sB;
#pragma unroll
    for (int q = 0; q < 8; ++q) {
        float4 a = hs[q];
        float4 b = hd[q];
        acc = fmaf(a.x, sW[q * 4 + 0], acc);
        acc = fmaf(a.y, sW[q * 4 + 1], acc);
        acc = fmaf(a.z, sW[q * 4 + 2], acc);
        acc = fmaf(a.w, sW[q * 4 + 3], acc);
        acc = fmaf(b.x, sW[H + q * 4 + 0], acc);
        acc = fmaf(b.y, sW[H + q * 4 + 1], acc);
        acc = fmaf(b.z, sW[H + q * 4 + 2], acc);
        acc = fmaf(b.w, sW[H + q * 4 + 3], acc);
    }
    float sc = 1.0f / (1.0f + __expf(-acc));
    __builtin_nontemporal_store(sc, &out[e]);
}

extern "C" void kernel_launch(void* const* d_in, const int* in_sizes, int n_in,
                              void* d_out, int out_size, void* d_ws, size_t ws_size,
                              hipStream_t stream) {
    const float* x_t   = (const float*)d_in[0];
    // d_in[1] (x_t_dt) unused by the reference
    const int*   eidx  = (const int*)d_in[2];
    const float* Wenc  = (const float*)d_in[3];
    const float* benc  = (const float*)d_in[4];
    const float* Wgcn  = (const float*)d_in[5];
    const float* bgcn  = (const float*)d_in[6];
    const float* Wedge = (const float*)d_in[7];
    const float* bedge = (const float*)d_in[8];
    float* out = (float*)d_out;

    const int* src = eidx;
    const int* dst = eidx + NE;

    char* ws = (char*)d_ws;

    if (ws_size >= 39300000) {
        // Layout (bytes):
        //   [0,        12.8M)  hW
        //   [12.8M,    25.6M)  csr_src
        //   [25.6M,    38.4M)  X region: deg16/wptr16 (6.4M) + degt (0.4M),
        //                      later reused as h2 (12.8M) — dead by k_gather.
        //   [38.4M, +0.4M+4)   row_ptr
        //   [38.8M+64, +0.4M)  dinv
        float* hW      = (float*)(ws);
        int*   csr_src = (int*)  (ws + 12800000);
        int*   deg16   = (int*)  (ws + 25600000);       // NS*NN*4 = 6,400,000
        int*   degt    = (int*)  (ws + 32000000);       //   400,000
        float* h2      = (float*)(ws + 25600000);       // aliases deg16+degt
        int*   row_ptr = (int*)  (ws + 38400000);       //   400,004
        float* dinv    = (float*)(ws + 38800064);       //   400,000

        hipMemsetAsync(deg16, 0, (size_t)NS * NN * sizeof(int), stream);

        k_encode<<<(NN + 255) / 256, 256, 0, stream>>>(x_t, Wenc, benc, Wgcn, hW);
        k_deg16<<<(NE + 255) / 256, 256, 0, stream>>>(dst, deg16);
        k_s1<<<(NN + 255) / 256, 256, 0, stream>>>(deg16, degt, dinv);
        k_s2<<<1, SCAN_T, 0, stream>>>(degt, row_ptr);
        k_s3<<<(NN + 255) / 256, 256, 0, stream>>>(deg16, row_ptr);
        k_fill16<<<(NE + 255) / 256, 256, 0, stream>>>(src, dst, deg16, csr_src);
        k_gather<<<(NN * 8 + 255) / 256, 256, 0, stream>>>(row_ptr, csr_src, dinv, hW, bgcn, h2);
        k_score<<<(NE + 255) / 256, 256, 0, stream>>>(src, dst, h2, Wedge, bedge, out);
    } else {
        // fallback: proven atomic-scatter path
        float* hW   = (float*)(ws);
        float* agg  = (float*)(ws + 12800000);
        int*   deg  = (int*)  (ws + 25600000);
        float* dinv = (float*)(ws + 26000256);

        hipMemsetAsync(agg, 0, (size_t)NN * H * sizeof(float), stream);
        hipMemsetAsync(deg, 0, (size_t)NN * sizeof(int), stream);

        k_encode<<<(NN + 255) / 256, 256, 0, stream>>>(x_t, Wenc, benc, Wgcn, hW);
        k_deg_fb<<<(NE + 255) / 256, 256, 0, stream>>>(dst, deg);
        k_dinv_fb<<<(NN + 255) / 256, 256, 0, stream>>>(deg, dinv);
        k_scatter_fb<<<(NE * 8 + 255) / 256, 256, 0, stream>>>(src, dst, dinv, hW, agg);
        k_final_fb<<<(NN * H + 255) / 256, 256, 0, stream>>>(agg, hW, dinv, bgcn);
        k_score<<<(NE + 255) / 256, 256, 0, stream>>>(src, dst, agg, Wedge, bedge, out);
    }
}

// Round 9
// 401.568 us; speedup vs baseline: 4.1992x; 2.2298x over previous
//
#include <hip/hip_runtime.h>
#include <math.h>

#define NN 100000
#define NE 3200000
#define IN_F 7
#define H 32

#define BSH 9                 // bucket shift: 512 nodes per bucket
#define BSPAN 512
#define NBUK ((NN + BSPAN - 1) / BSPAN)   // 196
#define EPB 8192              // edges per block in bucket passes

// ---------------- kernel 1: node encoder + GCN weight ----------------
__global__ __launch_bounds__(256) void k_encode(const float* __restrict__ x,
                                                const float* __restrict__ Wenc,
                                                const float* __restrict__ benc,
                                                const float* __restrict__ Wgcn,
                                                float* __restrict__ hW) {
    __shared__ float sWe[IN_F * H];
    __shared__ float sb[H];
    __shared__ float sWg[H * H];
    for (int i = threadIdx.x; i < IN_F * H; i += 256) sWe[i] = Wenc[i];
    for (int i = threadIdx.x; i < H; i += 256) sb[i] = benc[i];
    for (int i = threadIdx.x; i < H * H; i += 256) sWg[i] = Wgcn[i];
    __syncthreads();

    int n = blockIdx.x * 256 + threadIdx.x;
    if (n >= NN) return;

    float xl[IN_F];
#pragma unroll
    for (int j = 0; j < IN_F; ++j) xl[j] = x[n * IN_F + j];

    float h[H];
#pragma unroll
    for (int k = 0; k < H; ++k) {
        float a = sb[k];
#pragma unroll
        for (int j = 0; j < IN_F; ++j) a = fmaf(xl[j], sWe[j * H + k], a);
        h[k] = fmaxf(a, 0.f);
    }
#pragma unroll
    for (int k = 0; k < H; ++k) {
        float a = 0.f;
#pragma unroll
        for (int j = 0; j < H; ++j) a = fmaf(h[j], sWg[j * H + k], a);
        hW[n * H + k] = a;
    }
}

// ---------------- A0: bucket histogram (LDS, then 196 global adds/block) ----------
__global__ __launch_bounds__(1024) void k_bhist(const int* __restrict__ dst,
                                                int* __restrict__ bucket_cnt) {
    __shared__ int cnt[NBUK];
    for (int i = threadIdx.x; i < NBUK; i += 1024) cnt[i] = 0;
    __syncthreads();
    int base = blockIdx.x * EPB;
#pragma unroll
    for (int r = 0; r < EPB / 1024; ++r) {
        int e = base + r * 1024 + threadIdx.x;
        if (e < NE) atomicAdd(&cnt[dst[e] >> BSH], 1);
    }
    __syncthreads();
    for (int i = threadIdx.x; i < NBUK; i += 1024)
        if (cnt[i]) atomicAdd(&bucket_cnt[i], cnt[i]);
}

// ---------------- A1: scan 196 bucket counts -> base + cursor ----------------
__global__ __launch_bounds__(256) void k_bscan(const int* __restrict__ bucket_cnt,
                                               int* __restrict__ bucket_base,
                                               int* __restrict__ bucket_cur) {
    __shared__ int tmp[256];
    int t = threadIdx.x;
    int v = (t < NBUK) ? bucket_cnt[t] : 0;
    tmp[t] = v;
    __syncthreads();
    for (int off = 1; off < 256; off <<= 1) {
        int u = (t >= off) ? tmp[t - off] : 0;
        __syncthreads();
        tmp[t] += u;
        __syncthreads();
    }
    int ex = tmp[t] - v;  // exclusive prefix
    if (t < NBUK) {
        bucket_base[t] = ex;
        bucket_cur[t] = ex;
    }
    if (t == NBUK - 1) bucket_base[NBUK] = ex + v;  // == NE
}

// ---------------- A2: scatter packed pairs into bucket-contiguous storage --------
__global__ __launch_bounds__(1024) void k_bscatter(const int* __restrict__ src,
                                                   const int* __restrict__ dst,
                                                   int* __restrict__ bucket_cur,
                                                   unsigned int* __restrict__ pairs) {
    __shared__ int cnt[NBUK];
    __shared__ int cbase[NBUK];
    for (int i = threadIdx.x; i < NBUK; i += 1024) cnt[i] = 0;
    __syncthreads();
    int base = blockIdx.x * EPB;
#pragma unroll
    for (int r = 0; r < EPB / 1024; ++r) {
        int e = base + r * 1024 + threadIdx.x;
        if (e < NE) atomicAdd(&cnt[dst[e] >> BSH], 1);
    }
    __syncthreads();
    for (int i = threadIdx.x; i < NBUK; i += 1024) {
        int c = cnt[i];
        cbase[i] = c ? atomicAdd(&bucket_cur[i], c) : 0;
    }
    __syncthreads();
    for (int i = threadIdx.x; i < NBUK; i += 1024) cnt[i] = 0;  // reuse as local cursor
    __syncthreads();
#pragma unroll
    for (int r = 0; r < EPB / 1024; ++r) {
        int e = base + r * 1024 + threadIdx.x;
        if (e < NE) {
            int d = dst[e];
            int b = d >> BSH;
            int lp = atomicAdd(&cnt[b], 1);
            pairs[cbase[b] + lp] = ((unsigned int)src[e] << BSH) | (unsigned int)(d & (BSPAN - 1));
        }
    }
}

// ---------------- B: per-bucket deg/row_ptr/dinv + CSR fill (all LDS) ------------
__global__ __launch_bounds__(1024) void k_bfill(const unsigned int* __restrict__ pairs,
                                                const int* __restrict__ bucket_base,
                                                int* __restrict__ row_ptr,
                                                float* __restrict__ dinv,
                                                int* __restrict__ csr_src) {
    __shared__ int cnt[BSPAN];
    __shared__ int pre[BSPAN];
    int b = blockIdx.x;
    int ebeg = bucket_base[b], eend = bucket_base[b + 1];
    int t = threadIdx.x;
    for (int i = t; i < BSPAN; i += 1024) cnt[i] = 0;
    __syncthreads();
    for (int e = ebeg + t; e < eend; e += 1024)
        atomicAdd(&cnt[pairs[e] & (BSPAN - 1)], 1);
    __syncthreads();
    if (t < BSPAN) pre[t] = cnt[t];
    __syncthreads();
    for (int off = 1; off < BSPAN; off <<= 1) {
        int v = (t < BSPAN && t >= off) ? pre[t - off] : 0;
        __syncthreads();
        if (t < BSPAN) pre[t] += v;
        __syncthreads();
    }
    // pre = inclusive prefix; exclusive = pre - cnt
    int nbase = b * BSPAN;
    if (t < BSPAN) {
        int node = nbase + t;
        if (node < NN) {
            row_ptr[node] = ebeg + pre[t] - cnt[t];
            dinv[node] = rsqrtf((float)cnt[t] + 1.0f);
        }
    }
    if (b == NBUK - 1 && t == 0) row_ptr[NN] = NE;
    __syncthreads();
    if (t < BSPAN) cnt[t] = ebeg + pre[t] - cnt[t];  // global cursor per local node
    __syncthreads();
    for (int e = ebeg + t; e < eend; e += 1024) {
        unsigned int p = pairs[e];
        int pos = atomicAdd(&cnt[p & (BSPAN - 1)], 1);
        csr_src[pos] = (int)(p >> BSH);
    }
}

// ---------------- kernel 5: per-node gather + epilogue ----------------
__global__ __launch_bounds__(256) void k_gather(const int* __restrict__ row_ptr,
                                                const int* __restrict__ csr_src,
                                                const float* __restrict__ dinv,
                                                const float* __restrict__ hW,
                                                const float* __restrict__ bgcn,
                                                float* __restrict__ h2) {
    int tid = blockIdx.x * 256 + threadIdx.x;
    int n = tid >> 3;
    int c = tid & 7;
    if (n >= NN) return;
    float dn = dinv[n];
    int beg = row_ptr[n], end = row_ptr[n + 1];
    const float4* hW4 = reinterpret_cast<const float4*>(hW);
    float4 acc = make_float4(0.f, 0.f, 0.f, 0.f);
    for (int k = beg; k < end; ++k) {
        int s = csr_src[k];
        float nrm = dinv[s] * dn;
        float4 v = hW4[s * 8 + c];
        acc.x = fmaf(v.x, nrm, acc.x);
        acc.y = fmaf(v.y, nrm, acc.y);
        acc.z = fmaf(v.z, nrm, acc.z);
        acc.w = fmaf(v.w, nrm, acc.w);
    }
    float4 w = hW4[n * 8 + c];
    float sl = dn * dn;
    float4 bb = reinterpret_cast<const float4*>(bgcn)[c];
    float4 r;
    r.x = fmaxf(acc.x + w.x * sl + bb.x, 0.f);
    r.y = fmaxf(acc.y + w.y * sl + bb.y, 0.f);
    r.z = fmaxf(acc.z + w.z * sl + bb.z, 0.f);
    r.w = fmaxf(acc.w + w.w * sl + bb.w, 0.f);
    reinterpret_cast<float4*>(h2)[n * 8 + c] = r;
}

// ---------------- kernel 6: edge scorer ----------------
__global__ __launch_bounds__(256) void k_score(const int* __restrict__ src,
                                               const int* __restrict__ dst,
                                               const float* __restrict__ h2,
                                               const float* __restrict__ We,
                                               const float* __restrict__ be,
                                               float* __restrict__ out) {
    __shared__ float sW[2 * H];
    __shared__ float sB;
    if (threadIdx.x < 2 * H) sW[threadIdx.x] = We[threadIdx.x];
    if (threadIdx.x == 0) sB = be[0];
    __syncthreads();

    int e = blockIdx.x * 256 + threadIdx.x;
    if (e >= NE) return;
    int s = src[e];
    int d = dst[e];
    const float4* hs = reinterpret_cast<const float4*>(h2 + s * H);
    const float4* hd = reinterpret_cast<const float4*>(h2 + d * H);
    float acc = sB;
#pragma unroll
    for (int q = 0; q < 8; ++q) {
        float4 a = hs[q];
        float4 b = hd[q];
        acc = fmaf(a.x, sW[q * 4 + 0], acc);
        acc = fmaf(a.y, sW[q * 4 + 1], acc);
        acc = fmaf(a.z, sW[q * 4 + 2], acc);
        acc = fmaf(a.w, sW[q * 4 + 3], acc);
        acc = fmaf(b.x, sW[H + q * 4 + 0], acc);
        acc = fmaf(b.y, sW[H + q * 4 + 1], acc);
        acc = fmaf(b.z, sW[H + q * 4 + 2], acc);
        acc = fmaf(b.w, sW[H + q * 4 + 3], acc);
    }
    float sc = 1.0f / (1.0f + __expf(-acc));
    __builtin_nontemporal_store(sc, &out[e]);
}

// ---------------- fallback path kernels (proven round-3 CSR, global atomics) -----
#define SCAN_T 1024
#define CHUNK ((NN + SCAN_T - 1) / SCAN_T)

__global__ __launch_bounds__(256) void k_deg_fb(const int* __restrict__ dst,
                                                int* __restrict__ deg) {
    int e = blockIdx.x * 256 + threadIdx.x;
    if (e < NE) atomicAdd(&deg[dst[e]], 1);
}

__global__ __launch_bounds__(SCAN_T) void k_scan_fb(const int* __restrict__ deg,
                                                    int* __restrict__ row_ptr,
                                                    int* __restrict__ wptr,
                                                    float* __restrict__ dinv) {
    __shared__ int tmp[SCAN_T];
    int t = threadIdx.x;
    int base = t * CHUNK;
    int lim = min(base + CHUNK, NN);
    int s = 0;
    for (int i = base; i < lim; ++i) s += deg[i];
    tmp[t] = s;
    __syncthreads();
    for (int off = 1; off < SCAN_T; off <<= 1) {
        int v = (t >= off) ? tmp[t - off] : 0;
        __syncthreads();
        tmp[t] += v;
        __syncthreads();
    }
    int run = tmp[t] - s;
    for (int i = base; i < lim; ++i) {
        int d = deg[i];
        row_ptr[i] = run;
        wptr[i] = run;
        dinv[i] = rsqrtf((float)d + 1.0f);
        run += d;
    }
    if (t == SCAN_T - 1) row_ptr[NN] = run;
}

__global__ __launch_bounds__(256) void k_fill_fb(const int* __restrict__ src,
                                                 const int* __restrict__ dst,
                                                 int* __restrict__ wptr,
                                                 int* __restrict__ csr_src) {
    int e = blockIdx.x * 256 + threadIdx.x;
    if (e >= NE) return;
    int d = dst[e];
    int pos = atomicAdd(&wptr[d], 1);
    csr_src[pos] = src[e];
}

extern "C" void kernel_launch(void* const* d_in, const int* in_sizes, int n_in,
                              void* d_out, int out_size, void* d_ws, size_t ws_size,
                              hipStream_t stream) {
    const float* x_t   = (const float*)d_in[0];
    // d_in[1] (x_t_dt) unused by the reference
    const int*   eidx  = (const int*)d_in[2];
    const float* Wenc  = (const float*)d_in[3];
    const float* benc  = (const float*)d_in[4];
    const float* Wgcn  = (const float*)d_in[5];
    const float* bgcn  = (const float*)d_in[6];
    const float* Wedge = (const float*)d_in[7];
    const float* bedge = (const float*)d_in[8];
    float* out = (float*)d_out;

    const int* src = eidx;
    const int* dst = eidx + NE;

    char* ws = (char*)d_ws;

    if (ws_size >= 39210000) {
        // Layout (bytes):
        //   [0,        12.8M)   hW
        //   [12.8M,    25.6M)   pairs (uint32/edge)  -> reused as h2 after k_bfill
        //   [25.6M,    38.4M)   csr_src
        //   [38.4M,    +400004) row_ptr
        //   [38.8M+64, +400000) dinv
        //   [39.2M+64, ...)     bucket_cnt / bucket_base / bucket_cur
        float*        hW       = (float*)(ws);
        unsigned int* pairs    = (unsigned int*)(ws + 12800000);
        float*        h2       = (float*)(ws + 12800000);       // aliases pairs (pairs dead after k_bfill)
        int*          csr_src  = (int*)(ws + 25600000);
        int*          row_ptr  = (int*)(ws + 38400000);
        float*        dinv     = (float*)(ws + 38800064);
        int*          bucket_cnt  = (int*)(ws + 39200064);      // 784 B
        int*          bucket_base = (int*)(ws + 39201024);      // 788 B
        int*          bucket_cur  = (int*)(ws + 39202048);      // 784 B

        hipMemsetAsync(bucket_cnt, 0, NBUK * sizeof(int), stream);

        int ebks = (NE + EPB - 1) / EPB;  // 391
        k_encode<<<(NN + 255) / 256, 256, 0, stream>>>(x_t, Wenc, benc, Wgcn, hW);
        k_bhist<<<ebks, 1024, 0, stream>>>(dst, bucket_cnt);
        k_bscan<<<1, 256, 0, stream>>>(bucket_cnt, bucket_base, bucket_cur);
        k_bscatter<<<ebks, 1024, 0, stream>>>(src, dst, bucket_cur, pairs);
        k_bfill<<<NBUK, 1024, 0, stream>>>(pairs, bucket_base, row_ptr, dinv, csr_src);
        k_gather<<<(NN * 8 + 255) / 256, 256, 0, stream>>>(row_ptr, csr_src, dinv, hW, bgcn, h2);
        k_score<<<(NE + 255) / 256, 256, 0, stream>>>(src, dst, h2, Wedge, bedge, out);
    } else {
        // fallback: proven round-3 CSR path with global atomics
        float* hW_     = (float*)(ws);
        float* h2_     = (float*)(ws + 12800000);
        int*   csr_    = (int*)(ws + 25600000);
        int*   deg_    = (int*)(ws + 38400000);
        float* dinv_   = (float*)(ws + 38800000);
        int*   rowp_   = (int*)(ws + 39200000);
        int*   wptr_   = (int*)(ws + 39600064);

        hipMemsetAsync(deg_, 0, (size_t)NN * sizeof(int), stream);

        k_encode<<<(NN + 255) / 256, 256, 0, stream>>>(x_t, Wenc, benc, Wgcn, hW_);
        k_deg_fb<<<(NE + 255) / 256, 256, 0, stream>>>(dst, deg_);
        k_scan_fb<<<1, SCAN_T, 0, stream>>>(deg_, rowp_, wptr_, dinv_);
        k_fill_fb<<<(NE + 255) / 256, 256, 0, stream>>>(src, dst, wptr_, csr_);
        k_gather<<<(NN * 8 + 255) / 256, 256, 0, stream>>>(rowp_, csr_, dinv_, hW_, bgcn, h2_);
        k_score<<<(NE + 255) / 256, 256, 0, stream>>>(src, dst, h2_, Wedge, bedge, out);
    }
}

// Round 12
// 298.546 us; speedup vs baseline: 5.6483x; 1.3451x over previous
//
#include <hip/hip_runtime.h>
#include <hip/hip_fp16.h>
#include <math.h>

#define NN 100000
#define NE 3200000
#define IN_F 7
#define H 32

#define BSH 9                 // bucket shift: 512 nodes per bucket
#define BSPAN 512
#define NBUK ((NN + BSPAN - 1) / BSPAN)   // 196
#define EPB 8192              // edges per block in bucket passes

// ---------------- kernel 1: node encoder + GCN weight -> fp16 hW ----------------
__global__ __launch_bounds__(256) void k_encode(const float* __restrict__ x,
                                                const float* __restrict__ Wenc,
                                                const float* __restrict__ benc,
                                                const float* __restrict__ Wgcn,
                                                uint4* __restrict__ hW_h4) {
    __shared__ float sWe[IN_F * H];
    __shared__ float sb[H];
    __shared__ float sWg[H * H];
    for (int i = threadIdx.x; i < IN_F * H; i += 256) sWe[i] = Wenc[i];
    for (int i = threadIdx.x; i < H; i += 256) sb[i] = benc[i];
    for (int i = threadIdx.x; i < H * H; i += 256) sWg[i] = Wgcn[i];
    __syncthreads();

    int n = blockIdx.x * 256 + threadIdx.x;
    if (n >= NN) return;

    float xl[IN_F];
#pragma unroll
    for (int j = 0; j < IN_F; ++j) xl[j] = x[n * IN_F + j];

    float h[H];
#pragma unroll
    for (int k = 0; k < H; ++k) {
        float a = sb[k];
#pragma unroll
        for (int j = 0; j < IN_F; ++j) a = fmaf(xl[j], sWe[j * H + k], a);
        h[k] = fmaxf(a, 0.f);
    }
    float a[H];
#pragma unroll
    for (int k = 0; k < H; ++k) {
        float s = 0.f;
#pragma unroll
        for (int j = 0; j < H; ++j) s = fmaf(h[j], sWg[j * H + k], s);
        a[k] = s;
    }
    uint4 pk[4];
    __half2* hp = reinterpret_cast<__half2*>(pk);
#pragma unroll
    for (int k = 0; k < 16; ++k) hp[k] = __floats2half2_rn(a[2 * k], a[2 * k + 1]);
#pragma unroll
    for (int q = 0; q < 4; ++q) hW_h4[n * 4 + q] = pk[q];
}

// ---------------- A0: bucket histogram ----------------
__global__ __launch_bounds__(1024) void k_bhist(const int* __restrict__ dst,
                                                int* __restrict__ bucket_cnt) {
    __shared__ int cnt[NBUK];
    for (int i = threadIdx.x; i < NBUK; i += 1024) cnt[i] = 0;
    __syncthreads();
    int base = blockIdx.x * EPB;
#pragma unroll
    for (int r = 0; r < EPB / 1024; ++r) {
        int e = base + r * 1024 + threadIdx.x;
        if (e < NE) atomicAdd(&cnt[dst[e] >> BSH], 1);
    }
    __syncthreads();
    for (int i = threadIdx.x; i < NBUK; i += 1024)
        if (cnt[i]) atomicAdd(&bucket_cnt[i], cnt[i]);
}

// ---------------- A1: scan bucket counts -> base + cursor ----------------
__global__ __launch_bounds__(256) void k_bscan(const int* __restrict__ bucket_cnt,
                                               int* __restrict__ bucket_base,
                                               int* __restrict__ bucket_cur) {
    __shared__ int tmp[256];
    int t = threadIdx.x;
    int v = (t < NBUK) ? bucket_cnt[t] : 0;
    tmp[t] = v;
    __syncthreads();
    for (int off = 1; off < 256; off <<= 1) {
        int u = (t >= off) ? tmp[t - off] : 0;
        __syncthreads();
        tmp[t] += u;
        __syncthreads();
    }
    int ex = tmp[t] - v;
    if (t < NBUK) {
        bucket_base[t] = ex;
        bucket_cur[t] = ex;
    }
    if (t == NBUK - 1) bucket_base[NBUK] = ex + v;  // == NE
}

// ---------------- A2: scatter packed pairs into bucket-contiguous storage --------
__global__ __launch_bounds__(1024) void k_bscatter(const int* __restrict__ src,
                                                   const int* __restrict__ dst,
                                                   int* __restrict__ bucket_cur,
                                                   unsigned int* __restrict__ pairs) {
    __shared__ int cnt[NBUK];
    __shared__ int cbase[NBUK];
    for (int i = threadIdx.x; i < NBUK; i += 1024) cnt[i] = 0;
    __syncthreads();
    int base = blockIdx.x * EPB;
#pragma unroll
    for (int r = 0; r < EPB / 1024; ++r) {
        int e = base + r * 1024 + threadIdx.x;
        if (e < NE) atomicAdd(&cnt[dst[e] >> BSH], 1);
    }
    __syncthreads();
    for (int i = threadIdx.x; i < NBUK; i += 1024) {
        int c = cnt[i];
        cbase[i] = c ? atomicAdd(&bucket_cur[i], c) : 0;
    }
    __syncthreads();
    for (int i = threadIdx.x; i < NBUK; i += 1024) cnt[i] = 0;
    __syncthreads();
#pragma unroll
    for (int r = 0; r < EPB / 1024; ++r) {
        int e = base + r * 1024 + threadIdx.x;
        if (e < NE) {
            int d = dst[e];
            int b = d >> BSH;
            int lp = atomicAdd(&cnt[b], 1);
            pairs[cbase[b] + lp] = ((unsigned int)src[e] << BSH) | (unsigned int)(d & (BSPAN - 1));
        }
    }
}

// ---------------- B: per-bucket deg/row_ptr/dinv + CSR fill (all LDS) ------------
__global__ __launch_bounds__(1024) void k_bfill(const unsigned int* __restrict__ pairs,
                                                const int* __restrict__ bucket_base,
                                                int* __restrict__ row_ptr,
                                                float* __restrict__ dinv,
                                                int* __restrict__ csr_src) {
    __shared__ int cnt[BSPAN];
    __shared__ int pre[BSPAN];
    int b = blockIdx.x;
    int ebeg = bucket_base[b], eend = bucket_base[b + 1];
    int t = threadIdx.x;
    for (int i = t; i < BSPAN; i += 1024) cnt[i] = 0;
    __syncthreads();
    for (int e = ebeg + t; e < eend; e += 1024)
        atomicAdd(&cnt[pairs[e] & (BSPAN - 1)], 1);
    __syncthreads();
    if (t < BSPAN) pre[t] = cnt[t];
    __syncthreads();
    for (int off = 1; off < BSPAN; off <<= 1) {
        int v = (t < BSPAN && t >= off) ? pre[t - off] : 0;
        __syncthreads();
        if (t < BSPAN) pre[t] += v;
        __syncthreads();
    }
    int nbase = b * BSPAN;
    if (t < BSPAN) {
        int node = nbase + t;
        if (node < NN) {
            row_ptr[node] = ebeg + pre[t] - cnt[t];
            dinv[node] = rsqrtf((float)cnt[t] + 1.0f);
        }
    }
    if (b == NBUK - 1 && t == 0) row_ptr[NN] = NE;
    __syncthreads();
    if (t < BSPAN) cnt[t] = ebeg + pre[t] - cnt[t];
    __syncthreads();
    for (int e = ebeg + t; e < eend; e += 1024) {
        unsigned int p = pairs[e];
        int pos = atomicAdd(&cnt[p & (BSPAN - 1)], 1);
        csr_src[pos] = (int)(p >> BSH);
    }
}

// ---------------- kernel 5: per-node gather (4 lanes/node, fp16 in/out) ----------
__global__ __launch_bounds__(256) void k_gather(const int* __restrict__ row_ptr,
                                                const int* __restrict__ csr_src,
                                                const float* __restrict__ dinv,
                                                const uint4* __restrict__ hW_h4,
                                                const float* __restrict__ bgcn,
                                                uint4* __restrict__ h2_h4) {
    int tid = blockIdx.x * 256 + threadIdx.x;
    int n = tid >> 2;
    int c = tid & 3;          // lane owns halves [c*8, c*8+8)
    if (n >= NN) return;
    float dn = dinv[n];
    int beg = row_ptr[n], end = row_ptr[n + 1];
    float acc[8];
#pragma unroll
    for (int i = 0; i < 8; ++i) acc[i] = 0.f;
    for (int k = beg; k < end; ++k) {
        int s = csr_src[k];
        float nrm = dinv[s] * dn;
        uint4 v = hW_h4[s * 4 + c];
        const __half2* hp = reinterpret_cast<const __half2*>(&v);
#pragma unroll
        for (int i = 0; i < 4; ++i) {
            float2 f = __half22float2(hp[i]);
            acc[2 * i]     = fmaf(f.x, nrm, acc[2 * i]);
            acc[2 * i + 1] = fmaf(f.y, nrm, acc[2 * i + 1]);
        }
    }
    // self-loop + bias + relu
    float sl = dn * dn;
    uint4 w = hW_h4[n * 4 + c];
    const __half2* wp = reinterpret_cast<const __half2*>(&w);
    uint4 pk;
    __half2* op = reinterpret_cast<__half2*>(&pk);
#pragma unroll
    for (int i = 0; i < 4; ++i) {
        float2 f = __half22float2(wp[i]);
        float r0 = fmaxf(acc[2 * i]     + f.x * sl + bgcn[c * 8 + 2 * i],     0.f);
        float r1 = fmaxf(acc[2 * i + 1] + f.y * sl + bgcn[c * 8 + 2 * i + 1], 0.f);
        op[i] = __floats2half2_rn(r0, r1);
    }
    h2_h4[n * 4 + c] = pk;
}

// ---------------- kernel 6: edge scorer (4 lanes/edge, fp16 gathers) -------------
__global__ __launch_bounds__(256) void k_score(const int* __restrict__ src,
                                               const int* __restrict__ dst,
                                               const uint4* __restrict__ h2_h4,
                                               const float* __restrict__ We,
                                               const float* __restrict__ be,
                                               float* __restrict__ out) {
    __shared__ float sW[2 * H];
    __shared__ float sB;
    if (threadIdx.x < 2 * H) sW[threadIdx.x] = We[threadIdx.x];
    if (threadIdx.x == 0) sB = be[0];
    __syncthreads();

    int tid = blockIdx.x * 256 + threadIdx.x;
    int e = tid >> 2;
    int c = tid & 3;
    if (e >= NE) return;
    int s = src[e];
    int d = dst[e];
    uint4 av = h2_h4[s * 4 + c];
    uint4 bv = h2_h4[d * 4 + c];
    const __half2* ap = reinterpret_cast<const __half2*>(&av);
    const __half2* bp = reinterpret_cast<const __half2*>(&bv);
    float acc = 0.f;
#pragma unroll
    for (int i = 0; i < 4; ++i) {
        float2 fa = __half22float2(ap[i]);
        float2 fb = __half22float2(bp[i]);
        acc = fmaf(fa.x, sW[c * 8 + 2 * i],         acc);
        acc = fmaf(fa.y, sW[c * 8 + 2 * i + 1],     acc);
        acc = fmaf(fb.x, sW[H + c * 8 + 2 * i],     acc);
        acc = fmaf(fb.y, sW[H + c * 8 + 2 * i + 1], acc);
    }
    acc += __shfl_xor(acc, 1, 4);
    acc += __shfl_xor(acc, 2, 4);
    if (c == 0) {
        float sc = 1.0f / (1.0f + __expf(-(acc + sB)));
        __builtin_nontemporal_store(sc, &out[e]);
    }
}

extern "C" void kernel_launch(void* const* d_in, const int* in_sizes, int n_in,
                              void* d_out, int out_size, void* d_ws, size_t ws_size,
                              hipStream_t stream) {
    const float* x_t   = (const float*)d_in[0];
    // d_in[1] (x_t_dt) unused by the reference
    const int*   eidx  = (const int*)d_in[2];
    const float* Wenc  = (const float*)d_in[3];
    const float* benc  = (const float*)d_in[4];
    const float* Wgcn  = (const float*)d_in[5];
    const float* bgcn  = (const float*)d_in[6];
    const float* Wedge = (const float*)d_in[7];
    const float* bedge = (const float*)d_in[8];
    float* out = (float*)d_out;

    const int* src = eidx;
    const int* dst = eidx + NE;

    char* ws = (char*)d_ws;
    if (ws_size < 33000000) return;  // proven ws >= 39.2 MB in passing runs; can't happen

    // Layout (bytes):
    //   [0,          6.4M)    hW_h (fp16, 64 B/node)
    //   [6.4M+64,    19.2M)   pairs (uint32/edge); h2_h (6.4M) aliases its start
    //                         (pairs dead after k_bfill, h2 written by k_gather)
    //   [19.2M+128,  32.0M)   csr_src
    //   [32.0M+192,  +400004) row_ptr
    //   [32.4M+256,  +400000) dinv
    //   [32.8M+320 ..]        bucket_cnt / bucket_base / bucket_cur
    uint4*        hW_h4    = (uint4*)(ws);
    unsigned int* pairs    = (unsigned int*)(ws + 6400064);
    uint4*        h2_h4    = (uint4*)(ws + 6400064);
    int*          csr_src  = (int*)(ws + 19200128);
    int*          row_ptr  = (int*)(ws + 32000192);
    float*        dinv     = (float*)(ws + 32400256);
    int*          bucket_cnt  = (int*)(ws + 32800320);
    int*          bucket_base = (int*)(ws + 32801280);
    int*          bucket_cur  = (int*)(ws + 32802304);

    hipMemsetAsync(bucket_cnt, 0, NBUK * sizeof(int), stream);

    int ebks = (NE + EPB - 1) / EPB;  // 391
    k_encode<<<(NN + 255) / 256, 256, 0, stream>>>(x_t, Wenc, benc, Wgcn, hW_h4);
    k_bhist<<<ebks, 1024, 0, stream>>>(dst, bucket_cnt);
    k_bscan<<<1, 256, 0, stream>>>(bucket_cnt, bucket_base, bucket_cur);
    k_bscatter<<<ebks, 1024, 0, stream>>>(src, dst, bucket_cur, pairs);
    k_bfill<<<NBUK, 1024, 0, stream>>>(pairs, bucket_base, row_ptr, dinv, csr_src);
    k_gather<<<(NN * 4 + 255) / 256, 256, 0, stream>>>(row_ptr, csr_src, dinv, hW_h4, bgcn, h2_h4);
    k_score<<<((size_t)NE * 4 + 255) / 256, 256, 0, stream>>>(src, dst, h2_h4, Wedge, bedge, out);
}

// Round 13
// 265.613 us; speedup vs baseline: 6.3486x; 1.1240x over previous
//
#include <hip/hip_runtime.h>
#include <hip/hip_fp16.h>
#include <math.h>

#define NN 100000
#define NE 3200000
#define IN_F 7
#define H 32

#define BSH 9                 // bucket shift: 512 nodes per bucket
#define BSPAN 512
#define NBUK ((NN + BSPAN - 1) / BSPAN)   // 196
#define EPB 8192              // edges per block in bucket passes

// ---------------- kernel 1: node encoder + GCN weight -> fp16 hW ----------------
__global__ __launch_bounds__(256) void k_encode(const float* __restrict__ x,
                                                const float* __restrict__ Wenc,
                                                const float* __restrict__ benc,
                                                const float* __restrict__ Wgcn,
                                                uint4* __restrict__ hW_h4) {
    __shared__ float sWe[IN_F * H];
    __shared__ float sb[H];
    __shared__ float sWg[H * H];
    for (int i = threadIdx.x; i < IN_F * H; i += 256) sWe[i] = Wenc[i];
    for (int i = threadIdx.x; i < H; i += 256) sb[i] = benc[i];
    for (int i = threadIdx.x; i < H * H; i += 256) sWg[i] = Wgcn[i];
    __syncthreads();

    int n = blockIdx.x * 256 + threadIdx.x;
    if (n >= NN) return;

    float xl[IN_F];
#pragma unroll
    for (int j = 0; j < IN_F; ++j) xl[j] = x[n * IN_F + j];

    float h[H];
#pragma unroll
    for (int k = 0; k < H; ++k) {
        float a = sb[k];
#pragma unroll
        for (int j = 0; j < IN_F; ++j) a = fmaf(xl[j], sWe[j * H + k], a);
        h[k] = fmaxf(a, 0.f);
    }
    float a[H];
#pragma unroll
    for (int k = 0; k < H; ++k) {
        float s = 0.f;
#pragma unroll
        for (int j = 0; j < H; ++j) s = fmaf(h[j], sWg[j * H + k], s);
        a[k] = s;
    }
    uint4 pk[4];
    __half2* hp = reinterpret_cast<__half2*>(pk);
#pragma unroll
    for (int k = 0; k < 16; ++k) hp[k] = __floats2half2_rn(a[2 * k], a[2 * k + 1]);
#pragma unroll
    for (int q = 0; q < 4; ++q) hW_h4[n * 4 + q] = pk[q];
}

// ---------------- A0: bucket histogram ----------------
__global__ __launch_bounds__(1024) void k_bhist(const int* __restrict__ dst,
                                                int* __restrict__ bucket_cnt) {
    __shared__ int cnt[NBUK];
    for (int i = threadIdx.x; i < NBUK; i += 1024) cnt[i] = 0;
    __syncthreads();
    int base = blockIdx.x * EPB;
#pragma unroll
    for (int r = 0; r < EPB / 1024; ++r) {
        int e = base + r * 1024 + threadIdx.x;
        if (e < NE) atomicAdd(&cnt[dst[e] >> BSH], 1);
    }
    __syncthreads();
    for (int i = threadIdx.x; i < NBUK; i += 1024)
        if (cnt[i]) atomicAdd(&bucket_cnt[i], cnt[i]);
}

// ---------------- A1: scan bucket counts -> base + cursor ----------------
__global__ __launch_bounds__(256) void k_bscan(const int* __restrict__ bucket_cnt,
                                               int* __restrict__ bucket_base,
                                               int* __restrict__ bucket_cur) {
    __shared__ int tmp[256];
    int t = threadIdx.x;
    int v = (t < NBUK) ? bucket_cnt[t] : 0;
    tmp[t] = v;
    __syncthreads();
    for (int off = 1; off < 256; off <<= 1) {
        int u = (t >= off) ? tmp[t - off] : 0;
        __syncthreads();
        tmp[t] += u;
        __syncthreads();
    }
    int ex = tmp[t] - v;
    if (t < NBUK) {
        bucket_base[t] = ex;
        bucket_cur[t] = ex;
    }
    if (t == NBUK - 1) bucket_base[NBUK] = ex + v;  // == NE
}

// ---------------- A2: scatter packed pairs into bucket-contiguous storage --------
__global__ __launch_bounds__(1024) void k_bscatter(const int* __restrict__ src,
                                                   const int* __restrict__ dst,
                                                   int* __restrict__ bucket_cur,
                                                   unsigned int* __restrict__ pairs) {
    __shared__ int cnt[NBUK];
    __shared__ int cbase[NBUK];
    for (int i = threadIdx.x; i < NBUK; i += 1024) cnt[i] = 0;
    __syncthreads();
    int base = blockIdx.x * EPB;
#pragma unroll
    for (int r = 0; r < EPB / 1024; ++r) {
        int e = base + r * 1024 + threadIdx.x;
        if (e < NE) atomicAdd(&cnt[dst[e] >> BSH], 1);
    }
    __syncthreads();
    for (int i = threadIdx.x; i < NBUK; i += 1024) {
        int c = cnt[i];
        cbase[i] = c ? atomicAdd(&bucket_cur[i], c) : 0;
    }
    __syncthreads();
    for (int i = threadIdx.x; i < NBUK; i += 1024) cnt[i] = 0;
    __syncthreads();
#pragma unroll
    for (int r = 0; r < EPB / 1024; ++r) {
        int e = base + r * 1024 + threadIdx.x;
        if (e < NE) {
            int d = dst[e];
            int b = d >> BSH;
            int lp = atomicAdd(&cnt[b], 1);
            pairs[cbase[b] + lp] = ((unsigned int)src[e] << BSH) | (unsigned int)(d & (BSPAN - 1));
        }
    }
}

// ---------------- B: per-bucket deg/row_ptr/dinv + CSR fill (all LDS) ------------
__global__ __launch_bounds__(1024) void k_bfill(const unsigned int* __restrict__ pairs,
                                                const int* __restrict__ bucket_base,
                                                int* __restrict__ row_ptr,
                                                float* __restrict__ dinv,
                                                int* __restrict__ csr_src) {
    __shared__ int cnt[BSPAN];
    __shared__ int pre[BSPAN];
    int b = blockIdx.x;
    int ebeg = bucket_base[b], eend = bucket_base[b + 1];
    int t = threadIdx.x;
    for (int i = t; i < BSPAN; i += 1024) cnt[i] = 0;
    __syncthreads();
    for (int e = ebeg + t; e < eend; e += 1024)
        atomicAdd(&cnt[pairs[e] & (BSPAN - 1)], 1);
    __syncthreads();
    if (t < BSPAN) pre[t] = cnt[t];
    __syncthreads();
    for (int off = 1; off < BSPAN; off <<= 1) {
        int v = (t < BSPAN && t >= off) ? pre[t - off] : 0;
        __syncthreads();
        if (t < BSPAN) pre[t] += v;
        __syncthreads();
    }
    int nbase = b * BSPAN;
    if (t < BSPAN) {
        int node = nbase + t;
        if (node < NN) {
            row_ptr[node] = ebeg + pre[t] - cnt[t];
            dinv[node] = rsqrtf((float)cnt[t] + 1.0f);
        }
    }
    if (b == NBUK - 1 && t == 0) row_ptr[NN] = NE;
    __syncthreads();
    if (t < BSPAN) cnt[t] = ebeg + pre[t] - cnt[t];
    __syncthreads();
    for (int e = ebeg + t; e < eend; e += 1024) {
        unsigned int p = pairs[e];
        int pos = atomicAdd(&cnt[p & (BSPAN - 1)], 1);
        csr_src[pos] = (int)(p >> BSH);
    }
}

// ---------------- kernel 5: gather + epilogue + per-node edge-score halves -------
// 4 lanes/node. After computing the h2 slice in registers, each lane dots it
// against its slice of W_edge (src half and dst half), 4-lane shfl reduce,
// lane 0 writes ab[n] = (W_s . h2[n], W_d . h2[n]). h2 is never materialized.
__global__ __launch_bounds__(256) void k_gather(const int* __restrict__ row_ptr,
                                                const int* __restrict__ csr_src,
                                                const float* __restrict__ dinv,
                                                const uint4* __restrict__ hW_h4,
                                                const float* __restrict__ bgcn,
                                                const float* __restrict__ We,
                                                float2* __restrict__ ab) {
    int tid = blockIdx.x * 256 + threadIdx.x;
    int n = tid >> 2;
    int c = tid & 3;          // lane owns halves [c*8, c*8+8)
    if (n >= NN) return;
    float dn = dinv[n];
    int beg = row_ptr[n], end = row_ptr[n + 1];
    float acc[8];
#pragma unroll
    for (int i = 0; i < 8; ++i) acc[i] = 0.f;
    for (int k = beg; k < end; ++k) {
        int s = csr_src[k];
        float nrm = dinv[s] * dn;
        uint4 v = hW_h4[s * 4 + c];
        const __half2* hp = reinterpret_cast<const __half2*>(&v);
#pragma unroll
        for (int i = 0; i < 4; ++i) {
            float2 f = __half22float2(hp[i]);
            acc[2 * i]     = fmaf(f.x, nrm, acc[2 * i]);
            acc[2 * i + 1] = fmaf(f.y, nrm, acc[2 * i + 1]);
        }
    }
    // self-loop + bias + relu, then per-node scorer halves
    float sl = dn * dn;
    uint4 w = hW_h4[n * 4 + c];
    const __half2* wp = reinterpret_cast<const __half2*>(&w);
    float dota = 0.f, dotb = 0.f;
#pragma unroll
    for (int i = 0; i < 4; ++i) {
        float2 f = __half22float2(wp[i]);
        float r0 = fmaxf(acc[2 * i]     + f.x * sl + bgcn[c * 8 + 2 * i],     0.f);
        float r1 = fmaxf(acc[2 * i + 1] + f.y * sl + bgcn[c * 8 + 2 * i + 1], 0.f);
        dota = fmaf(r0, We[c * 8 + 2 * i],         dota);
        dota = fmaf(r1, We[c * 8 + 2 * i + 1],     dota);
        dotb = fmaf(r0, We[H + c * 8 + 2 * i],     dotb);
        dotb = fmaf(r1, We[H + c * 8 + 2 * i + 1], dotb);
    }
    dota += __shfl_xor(dota, 1, 4);
    dota += __shfl_xor(dota, 2, 4);
    dotb += __shfl_xor(dotb, 1, 4);
    dotb += __shfl_xor(dotb, 2, 4);
    if (c == 0) ab[n] = make_float2(dota, dotb);
}

// ---------------- kernel 6: edge scorer = two 8B table lookups + sigmoid ---------
__global__ __launch_bounds__(256) void k_edge(const int* __restrict__ src,
                                              const int* __restrict__ dst,
                                              const float2* __restrict__ ab,
                                              const float* __restrict__ be,
                                              float* __restrict__ out) {
    int e = blockIdx.x * 256 + threadIdx.x;
    if (e >= NE) return;
    float logit = ab[src[e]].x + ab[dst[e]].y + be[0];
    float sc = 1.0f / (1.0f + __expf(-logit));
    __builtin_nontemporal_store(sc, &out[e]);
}

extern "C" void kernel_launch(void* const* d_in, const int* in_sizes, int n_in,
                              void* d_out, int out_size, void* d_ws, size_t ws_size,
                              hipStream_t stream) {
    const float* x_t   = (const float*)d_in[0];
    // d_in[1] (x_t_dt) unused by the reference
    const int*   eidx  = (const int*)d_in[2];
    const float* Wenc  = (const float*)d_in[3];
    const float* benc  = (const float*)d_in[4];
    const float* Wgcn  = (const float*)d_in[5];
    const float* bgcn  = (const float*)d_in[6];
    const float* Wedge = (const float*)d_in[7];
    const float* bedge = (const float*)d_in[8];
    float* out = (float*)d_out;

    const int* src = eidx;
    const int* dst = eidx + NE;

    char* ws = (char*)d_ws;
    if (ws_size < 33700000) return;  // proven ws >= 39.2 MB in passing runs; can't happen

    // Layout (bytes), no aliasing needed:
    //   [0,          6.4M)    hW_h (fp16, 64 B/node)
    //   [6.4M+64,    19.2M)   pairs (uint32/edge)
    //   [19.2M+128,  32.0M)   csr_src
    //   [32.0M+192,  +400004) row_ptr
    //   [32.4M+256,  +400000) dinv
    //   [32.8M+320,  +800000) ab (float2/node)
    //   [33.6M+384 ..]        bucket_cnt / bucket_base / bucket_cur
    uint4*        hW_h4    = (uint4*)(ws);
    unsigned int* pairs    = (unsigned int*)(ws + 6400064);
    int*          csr_src  = (int*)(ws + 19200128);
    int*          row_ptr  = (int*)(ws + 32000192);
    float*        dinv     = (float*)(ws + 32400256);
    float2*       ab       = (float2*)(ws + 32800320);
    int*          bucket_cnt  = (int*)(ws + 33600384);
    int*          bucket_base = (int*)(ws + 33601344);
    int*          bucket_cur  = (int*)(ws + 33602368);

    hipMemsetAsync(bucket_cnt, 0, NBUK * sizeof(int), stream);

    int ebks = (NE + EPB - 1) / EPB;  // 391
    k_encode<<<(NN + 255) / 256, 256, 0, stream>>>(x_t, Wenc, benc, Wgcn, hW_h4);
    k_bhist<<<ebks, 1024, 0, stream>>>(dst, bucket_cnt);
    k_bscan<<<1, 256, 0, stream>>>(bucket_cnt, bucket_base, bucket_cur);
    k_bscatter<<<ebks, 1024, 0, stream>>>(src, dst, bucket_cur, pairs);
    k_bfill<<<NBUK, 1024, 0, stream>>>(pairs, bucket_base, row_ptr, dinv, csr_src);
    k_gather<<<(NN * 4 + 255) / 256, 256, 0, stream>>>(row_ptr, csr_src, dinv, hW_h4, bgcn, Wedge, ab);
    k_edge<<<(NE + 255) / 256, 256, 0, stream>>>(src, dst, ab, bedge, out);
}